// Round 4
// baseline (122.338 us; speedup 1.0000x reference)
//
#include <hip/hip_runtime.h>

#define T_LEN 262144
#define R_LEN 4000
#define NCH 64
#define NCHUNK 253       // table chunks t in [0,253); nonzero only [0,252); 252 = zeros
#define NSLOT 4624       // permuted 16B staging slots (2312 blocks x 2)
#define LDS_BYTES 73984  // 2312 blocks x 32B; perm(beta) = (beta>>3) + (beta&7)*289

typedef __attribute__((ext_vector_type(8))) short bf16x8;
typedef __attribute__((ext_vector_type(16))) float f32x16;

static __device__ __forceinline__ unsigned short f2bf(float f) {
  unsigned u = __builtin_bit_cast(unsigned, f);
  unsigned r = 0x7FFFu + ((u >> 16) & 1u);
  return (unsigned short)((u + r) >> 16);
}

// T[t][j,h,e] = k[4000 + j - 16t - 8h - e] (zero outside [0,4000))
// stored: btf[((ch*253 + t)*64 + lane)*8 + e], j = lane&31, h = lane>>5
__global__ __launch_bounds__(256) void build_btf(const float* __restrict__ src,
                                                 unsigned short* __restrict__ btf) {
  int t0 = blockIdx.x * 256 + threadIdx.x;
  if (t0 >= NCH * NCHUNK * 64) return;
  int lane = t0 & 63;
  int t = (t0 >> 6) % NCHUNK;
  int ch = t0 / (64 * NCHUNK);
  int j = lane & 31;
  int h = lane >> 5;
  int kbase = 4000 + j - 16 * t - 8 * h;
  const float* k = src + (size_t)ch * R_LEN;
  unsigned short vals[8];
#pragma unroll
  for (int e = 0; e < 8; ++e) {
    int r = kbase - e;
    float f = (r >= 0 && r < R_LEN) ? k[r] : 0.0f;
    vals[e] = f2bf(f);
  }
  unsigned int* dst = (unsigned int*)(btf + (size_t)t0 * 8);
  dst[0] = (unsigned int)vals[0] | ((unsigned int)vals[1] << 16);
  dst[1] = (unsigned int)vals[2] | ((unsigned int)vals[3] << 16);
  dst[2] = (unsigned int)vals[4] | ((unsigned int)vals[5] << 16);
  dst[3] = (unsigned int)vals[6] | ((unsigned int)vals[7] << 16);
}

// Block (512 thr, 8 waves): ch = bid&63, piece = bid>>6, T0 = piece*32768.
// Wave w: 4096 outputs. D_c[i][j] = out[T0 + 4096w + 128i + 32c + j] = sum_q A_q[i] . T[q-2c]
// A_q lane(i,h): window elem u = 4096w + 128i + 16q + 8h (+e), u <-> x[T0-4000+u].
// LDS layout: 32B-block beta at permuted block (beta>>3) + (beta&7)*289 -> wave A-reads
// are 1024B contiguous. Staging iterates PERMUTED slot n: writes contiguous (0 conflicts),
// global reads scatter in 64B segments.
__global__ __launch_bounds__(512, 4) void conv_main(const float* __restrict__ x,
                                                    const unsigned short* __restrict__ btf,
                                                    float* __restrict__ out) {
  __shared__ alignas(16) unsigned char xs[LDS_BYTES];
  const int bid = blockIdx.x;
  const int ch = bid & 63;          // 8 pieces of a channel share bid%8 -> same XCD
  const int T0 = (bid >> 6) << 15;
  const float* xch = x + (size_t)ch * T_LEN;

  // Stage: permuted slot n (byte 16n) <- bf16(x[T0-4000+8s .. +8)), s = 2*(8q+r)+(n&1),
  // where q = (n>>1) % 289, r = (n>>1) / 289.
  for (int n = threadIdx.x; n < NSLOT; n += 512) {
    int pb = n >> 1;
    int r = pb / 289;
    int q = pb - 289 * r;
    int s = 2 * (8 * q + r) + (n & 1);
    int gi = T0 - 4000 + 8 * s;
    float v0, v1, v2, v3, v4, v5, v6, v7;
    if (gi >= 0 && gi + 8 <= T_LEN) {
      float4 a = *(const float4*)(xch + gi);
      float4 b = *(const float4*)(xch + gi + 4);
      v0 = a.x; v1 = a.y; v2 = a.z; v3 = a.w;
      v4 = b.x; v5 = b.y; v6 = b.z; v7 = b.w;
    } else {
      v0 = (gi + 0 >= 0 && gi + 0 < T_LEN) ? xch[gi + 0] : 0.f;
      v1 = (gi + 1 >= 0 && gi + 1 < T_LEN) ? xch[gi + 1] : 0.f;
      v2 = (gi + 2 >= 0 && gi + 2 < T_LEN) ? xch[gi + 2] : 0.f;
      v3 = (gi + 3 >= 0 && gi + 3 < T_LEN) ? xch[gi + 3] : 0.f;
      v4 = (gi + 4 >= 0 && gi + 4 < T_LEN) ? xch[gi + 4] : 0.f;
      v5 = (gi + 5 >= 0 && gi + 5 < T_LEN) ? xch[gi + 5] : 0.f;
      v6 = (gi + 6 >= 0 && gi + 6 < T_LEN) ? xch[gi + 6] : 0.f;
      v7 = (gi + 7 >= 0 && gi + 7 < T_LEN) ? xch[gi + 7] : 0.f;
    }
    uint4 pk;
    pk.x = (unsigned int)f2bf(v0) | ((unsigned int)f2bf(v1) << 16);
    pk.y = (unsigned int)f2bf(v2) | ((unsigned int)f2bf(v3) << 16);
    pk.z = (unsigned int)f2bf(v4) | ((unsigned int)f2bf(v5) << 16);
    pk.w = (unsigned int)f2bf(v6) | ((unsigned int)f2bf(v7) << 16);
    *(uint4*)(xs + 16 * n) = pk;
  }
  __syncthreads();

  const int lane = threadIdx.x & 63;
  const int w = threadIdx.x >> 6;
  const int i = lane & 31;
  const int h = lane >> 5;
  const int lanepart = 32 * i + 16 * h;
  const char* bbase = (const char*)btf + ((size_t)ch * NCHUNK) * 1024 + (size_t)lane * 16;

  auto aread = [&](int q) -> bf16x8 {
    int b0 = 256 * w + q;
    int addr = (((b0 >> 3) + (b0 & 7) * 289) << 5) + lanepart;
    return *(const bf16x8*)(xs + addr);
  };
  auto bload = [&](int t) -> bf16x8 {
    int tc = t > 252 ? 252 : t;   // T[252] is all-zero padding
    return *(const bf16x8*)(bbase + (size_t)tc * 1024);
  };

  f32x16 acc[4] = {};
  bf16x8 zero8 = {};
  bf16x8 E0 = bload(0), E1 = zero8, E2 = zero8, E3 = zero8;
  bf16x8 O0 = bload(1), O1 = zero8, O2 = zero8, O3 = zero8;
  bf16x8 a = aread(0);

#define DO_STEP(B0, B1, B2, B3, QQ)                                                      \
  {                                                                                      \
    bf16x8 nb = bload((QQ) + 2);                                                         \
    bf16x8 an = aread((QQ) + 1);                                                         \
    acc[0] = __builtin_amdgcn_mfma_f32_32x32x16_bf16(a, B0, acc[0], 0, 0, 0);            \
    acc[1] = __builtin_amdgcn_mfma_f32_32x32x16_bf16(a, B1, acc[1], 0, 0, 0);            \
    acc[2] = __builtin_amdgcn_mfma_f32_32x32x16_bf16(a, B2, acc[2], 0, 0, 0);            \
    acc[3] = __builtin_amdgcn_mfma_f32_32x32x16_bf16(a, B3, acc[3], 0, 0, 0);            \
    B3 = B2; B2 = B1; B1 = B0; B0 = nb;                                                  \
    a = an;                                                                              \
  }

#pragma unroll 4
  for (int q = 0; q < 258; q += 2) {
    DO_STEP(E0, E1, E2, E3, q);
    DO_STEP(O0, O1, O2, O3, q + 1);
  }
#undef DO_STEP

  // C/D layout: col j = lane&31, row = (r&3) + 8*(r>>2) + 4*h
  float* och = out + (size_t)ch * T_LEN + T0 + 4096 * w;
#pragma unroll
  for (int c = 0; c < 4; ++c) {
#pragma unroll
    for (int r = 0; r < 16; ++r) {
      int row = (r & 3) + 8 * (r >> 2) + 4 * h;
      och[32 * c + 128 * row + i] = acc[c][r];
    }
  }
}

extern "C" void kernel_launch(void* const* d_in, const int* in_sizes, int n_in,
                              void* d_out, int out_size, void* d_ws, size_t ws_size,
                              hipStream_t stream) {
  const float* onsets  = (const float*)d_in[0];
  const float* sources = (const float*)d_in[1];
  unsigned short* btf  = (unsigned short*)d_ws;   // 64*253*64*8*2 = 16,580,608 B
  float* out = (float*)d_out;

  int nthr = NCH * NCHUNK * 64;
  build_btf<<<(nthr + 255) / 256, 256, 0, stream>>>(sources, btf);
  conv_main<<<512, 512, 0, stream>>>(onsets, btf, out);
}

// Round 5
// 118.798 us; speedup vs baseline: 1.0298x; 1.0298x over previous
//
#include <hip/hip_runtime.h>

#define T_LEN 262144
#define R_LEN 4000
#define NCH 64
#define NCHUNK 253       // B chunks t in [0,253); T[252] = zeros (clamp target)
#define PERM_C 161
#define NBLK 1288        // permuted 32B A-blocks; perm(beta)=(beta>>3)+(beta&7)*161
#define A_BYTES (NBLK * 32)          // 41216
#define NSLOT (NBLK * 2)             // 2576 16B staging slots
#define RING_OFF A_BYTES
#define LDS_BYTES (A_BYTES + 16384)  // + 2 x 8KB B-ring = 57600
#define NPHASE 32                    // steps: 6 prologue + 32*8 = 262

typedef __attribute__((ext_vector_type(8))) short bf16x8;
typedef __attribute__((ext_vector_type(16))) float f32x16;

static __device__ __forceinline__ unsigned short f2bf(float f) {
  unsigned u = __builtin_bit_cast(unsigned, f);
  unsigned r = 0x7FFFu + ((u >> 16) & 1u);
  return (unsigned short)((u + r) >> 16);
}

// T[t][j,h,e] = k[4000 + j - 16t - 8h - e] (zero outside [0,4000))
// stored: btf[((ch*253 + t)*64 + lane)*8 + e], j = lane&31, h = lane>>5
__global__ __launch_bounds__(256) void build_btf(const float* __restrict__ src,
                                                 unsigned short* __restrict__ btf) {
  int t0 = blockIdx.x * 256 + threadIdx.x;
  if (t0 >= NCH * NCHUNK * 64) return;
  int lane = t0 & 63;
  int t = (t0 >> 6) % NCHUNK;
  int ch = t0 / (64 * NCHUNK);
  int j = lane & 31;
  int h = lane >> 5;
  int kbase = 4000 + j - 16 * t - 8 * h;
  const float* k = src + (size_t)ch * R_LEN;
  unsigned short vals[8];
#pragma unroll
  for (int e = 0; e < 8; ++e) {
    int r = kbase - e;
    float f = (r >= 0 && r < R_LEN) ? k[r] : 0.0f;
    vals[e] = f2bf(f);
  }
  unsigned int* dst = (unsigned int*)(btf + (size_t)t0 * 8);
  dst[0] = (unsigned int)vals[0] | ((unsigned int)vals[1] << 16);
  dst[1] = (unsigned int)vals[2] | ((unsigned int)vals[3] << 16);
  dst[2] = (unsigned int)vals[4] | ((unsigned int)vals[5] << 16);
  dst[3] = (unsigned int)vals[6] | ((unsigned int)vals[7] << 16);
}

// Block (256 thr, 4 waves): ch = bid&63, piece = bid>>6 (16 pieces), T0 = piece*16384.
// Wave w: 4096 outputs. D_c[i][j] = out[T0 + 4096w + 128i + 32c + j] = sum_q A_q[i].T[q-2c]
// A window elem u <-> x[T0-4000+u]; 32B-block beta at permuted slot (beta>>3)+(beta&7)*161.
// B: double-buffered 8-chunk LDS ring, staged per phase (issue-early, write-late).
__global__ __launch_bounds__(256, 2) void conv_main(const float* __restrict__ x,
                                                    const unsigned short* __restrict__ btf,
                                                    float* __restrict__ out) {
  __shared__ alignas(16) unsigned char xs[LDS_BYTES];
  const int bid = blockIdx.x;
  const int ch = bid & 63;          // all 16 pieces of a channel share bid%8 -> same XCD
  const int T0 = (bid >> 6) << 14;
  const float* xch = x + (size_t)ch * T_LEN;
  const char* btc = (const char*)btf + (size_t)ch * NCHUNK * 1024;

  const int tid = threadIdx.x;
  const int lane = tid & 63;
  const int w = tid >> 6;

  // ---- A staging: contiguous LDS writes at permuted slot n; scattered global reads
  for (int n = tid; n < NSLOT; n += 256) {
    int pb = n >> 1;
    int r = pb / PERM_C;
    int q = pb - PERM_C * r;
    int s = 2 * (8 * q + r) + (n & 1);
    int gi = T0 - 4000 + 8 * s;
    float v0, v1, v2, v3, v4, v5, v6, v7;
    if (gi >= 0 && gi + 8 <= T_LEN) {
      float4 a = *(const float4*)(xch + gi);
      float4 b = *(const float4*)(xch + gi + 4);
      v0 = a.x; v1 = a.y; v2 = a.z; v3 = a.w;
      v4 = b.x; v5 = b.y; v6 = b.z; v7 = b.w;
    } else {
      v0 = (gi + 0 >= 0 && gi + 0 < T_LEN) ? xch[gi + 0] : 0.f;
      v1 = (gi + 1 >= 0 && gi + 1 < T_LEN) ? xch[gi + 1] : 0.f;
      v2 = (gi + 2 >= 0 && gi + 2 < T_LEN) ? xch[gi + 2] : 0.f;
      v3 = (gi + 3 >= 0 && gi + 3 < T_LEN) ? xch[gi + 3] : 0.f;
      v4 = (gi + 4 >= 0 && gi + 4 < T_LEN) ? xch[gi + 4] : 0.f;
      v5 = (gi + 5 >= 0 && gi + 5 < T_LEN) ? xch[gi + 5] : 0.f;
      v6 = (gi + 6 >= 0 && gi + 6 < T_LEN) ? xch[gi + 6] : 0.f;
      v7 = (gi + 7 >= 0 && gi + 7 < T_LEN) ? xch[gi + 7] : 0.f;
    }
    uint4 pk;
    pk.x = (unsigned int)f2bf(v0) | ((unsigned int)f2bf(v1) << 16);
    pk.y = (unsigned int)f2bf(v2) | ((unsigned int)f2bf(v3) << 16);
    pk.z = (unsigned int)f2bf(v4) | ((unsigned int)f2bf(v5) << 16);
    pk.w = (unsigned int)f2bf(v6) | ((unsigned int)f2bf(v7) << 16);
    *(uint4*)(xs + 16 * n) = pk;
  }

  // ---- B prologue: groups 0 (chunks 0-7) and 1 (chunks 8-15); wave w covers 2w, 2w+1
#pragma unroll
  for (int g = 0; g < 2; ++g) {
#pragma unroll
    for (int k = 0; k < 2; ++k) {
      int t = 8 * g + 2 * w + k;
      uint4 r = *(const uint4*)(btc + (size_t)t * 1024 + lane * 16);
      *(uint4*)(xs + RING_OFF + g * 8192 + (2 * w + k) * 1024 + lane * 16) = r;
    }
  }
  __syncthreads();

  const int i = lane & 31;
  const int h = lane >> 5;
  const int lanepart = 32 * i + 16 * h;

  auto aread = [&](int q) -> bf16x8 {
    int b0 = 256 * w + q;
    int addr = (((b0 >> 3) + (b0 & 7) * PERM_C) << 5) + lanepart;
    return *(const bf16x8*)(xs + addr);
  };
  auto ldsB = [&](int t) -> bf16x8 {
    return *(const bf16x8*)(xs + RING_OFF + ((t >> 3) & 1) * 8192 + (t & 7) * 1024 + lane * 16);
  };

  f32x16 acc[4] = {};
  bf16x8 zero8 = {};
  bf16x8 E0 = ldsB(0), E1 = zero8, E2 = zero8, E3 = zero8;
  bf16x8 O0 = ldsB(1), O1 = zero8, O2 = zero8, O3 = zero8;
  bf16x8 a_cur = aread(0), a_n1 = aread(1);

#define DO_STEP(B0, B1, B2, B3, QQ)                                                      \
  {                                                                                      \
    bf16x8 nb = ldsB((QQ) + 2);                                                          \
    bf16x8 a2 = aread((QQ) + 2);                                                         \
    acc[0] = __builtin_amdgcn_mfma_f32_32x32x16_bf16(a_cur, B0, acc[0], 0, 0, 0);        \
    acc[1] = __builtin_amdgcn_mfma_f32_32x32x16_bf16(a_cur, B1, acc[1], 0, 0, 0);        \
    acc[2] = __builtin_amdgcn_mfma_f32_32x32x16_bf16(a_cur, B2, acc[2], 0, 0, 0);        \
    acc[3] = __builtin_amdgcn_mfma_f32_32x32x16_bf16(a_cur, B3, acc[3], 0, 0, 0);        \
    B3 = B2; B2 = B1; B1 = B0; B0 = nb;                                                  \
    a_cur = a_n1; a_n1 = a2;                                                             \
  }

  // prologue compute: steps 0..5 (consume group 0)
#pragma unroll
  for (int ii = 0; ii < 3; ++ii) {
    DO_STEP(E0, E1, E2, E3, 2 * ii);
    DO_STEP(O0, O1, O2, O3, 2 * ii + 1);
  }

  // phases p: steps [6+8p, 14+8p) consume group p+1; stage group p+2 into buf[p&1]
  for (int p = 0; p < NPHASE; ++p) {
    int gt = 8 * (p + 2) + 2 * w;
    int t0c = gt > 252 ? 252 : gt;          // clamp: chunks >= 252 are zeros
    int t1c = gt + 1 > 252 ? 252 : gt + 1;
    uint4 r0 = *(const uint4*)(btc + (size_t)t0c * 1024 + lane * 16);
    uint4 r1 = *(const uint4*)(btc + (size_t)t1c * 1024 + lane * 16);
    int qb = 6 + 8 * p;
#pragma unroll
    for (int ii = 0; ii < 4; ++ii) {
      DO_STEP(E0, E1, E2, E3, qb + 2 * ii);
      DO_STEP(O0, O1, O2, O3, qb + 2 * ii + 1);
    }
    char* dst = (char*)xs + RING_OFF + (p & 1) * 8192 + 2 * w * 1024 + lane * 16;
    *(uint4*)dst = r0;
    *(uint4*)(dst + 1024) = r1;
    __syncthreads();
  }
#undef DO_STEP

  // C/D layout: col j = lane&31, row = (r&3) + 8*(r>>2) + 4*h
  float* och = out + (size_t)ch * T_LEN + T0 + 4096 * w;
#pragma unroll
  for (int c = 0; c < 4; ++c) {
#pragma unroll
    for (int r = 0; r < 16; ++r) {
      int row = (r & 3) + 8 * (r >> 2) + 4 * h;
      och[32 * c + 128 * row + i] = acc[c][r];
    }
  }
}

extern "C" void kernel_launch(void* const* d_in, const int* in_sizes, int n_in,
                              void* d_out, int out_size, void* d_ws, size_t ws_size,
                              hipStream_t stream) {
  const float* onsets  = (const float*)d_in[0];
  const float* sources = (const float*)d_in[1];
  unsigned short* btf  = (unsigned short*)d_ws;   // 64*253*64*8*2 = 16,580,608 B
  float* out = (float*)d_out;

  int nthr = NCH * NCHUNK * 64;
  build_btf<<<(nthr + 255) / 256, 256, 0, stream>>>(sources, btf);
  conv_main<<<1024, 256, 0, stream>>>(onsets, btf, out);
}

// Round 6
// 117.979 us; speedup vs baseline: 1.0369x; 1.0069x over previous
//
#include <hip/hip_runtime.h>

#define T_LEN 262144
#define R_LEN 4000
#define NCH 64
#define NCHUNK 253       // B chunks t in [0,253); T[252] = zeros (clamp target)
#define WBLK 4616        // staged 16B-blocks (covers aread up to step 273)
#define SIG_M 145        // sigma(beta) = (beta>>5) + 145*(beta&31), injective for beta<4640
#define LDS_BYTES 74240  // sigma_max = 144 + 145*31 = 4639 -> 4640 slots x 16B
#define NSTEP 272        // 17 x 16-step unroll; steps >= 266 use T[252]=0

typedef __attribute__((ext_vector_type(8))) short bf16x8;
typedef __attribute__((ext_vector_type(16))) float f32x16;

static __device__ __forceinline__ unsigned short f2bf(float f) {
  unsigned u = __builtin_bit_cast(unsigned, f);
  unsigned r = 0x7FFFu + ((u >> 16) & 1u);
  return (unsigned short)((u + r) >> 16);
}

// T[t][j,h,e] = k[4000 + j - 16t - 8h - e] (zero outside [0,4000))
// stored: btf[((ch*253 + t)*64 + lane)*8 + e], j = lane&31, h = lane>>5
__global__ __launch_bounds__(256) void build_btf(const float* __restrict__ src,
                                                 unsigned short* __restrict__ btf) {
  int t0 = blockIdx.x * 256 + threadIdx.x;
  if (t0 >= NCH * NCHUNK * 64) return;
  int lane = t0 & 63;
  int t = (t0 >> 6) % NCHUNK;
  int ch = t0 / (64 * NCHUNK);
  int j = lane & 31;
  int h = lane >> 5;
  int kbase = 4000 + j - 16 * t - 8 * h;
  const float* k = src + (size_t)ch * R_LEN;
  unsigned short vals[8];
#pragma unroll
  for (int e = 0; e < 8; ++e) {
    int r = kbase - e;
    float f = (r >= 0 && r < R_LEN) ? k[r] : 0.0f;
    vals[e] = f2bf(f);
  }
  unsigned int* dst = (unsigned int*)(btf + (size_t)t0 * 8);
  dst[0] = (unsigned int)vals[0] | ((unsigned int)vals[1] << 16);
  dst[1] = (unsigned int)vals[2] | ((unsigned int)vals[3] << 16);
  dst[2] = (unsigned int)vals[4] | ((unsigned int)vals[5] << 16);
  dst[3] = (unsigned int)vals[6] | ((unsigned int)vals[7] << 16);
}

// Block (256 thr, 4 waves): ch = bid&63, piece = bid>>6 (8 pieces), T0 = piece*32768.
// Wave w: W0 = T0 + 8192w, outputs out[W0 + 256i + 32c + j], i,j in [0,32), c in [0,8).
// D_c[i][j] = sum_q A_q[i] . T[q-2c];  A frag (i=lane&31, h): x[W0-4000+256i+16q+8h+e].
// Window elem u staged at sigma-permuted LDS slot; A-reads = 2x contiguous 512B, 0 VALU.
// Main loop: NO barriers; 8-MFMA clusters under setprio; B from global (L1-shared).
__global__ __launch_bounds__(256, 2) void conv_main(const float* __restrict__ x,
                                                    const unsigned short* __restrict__ btf,
                                                    float* __restrict__ out) {
  __shared__ alignas(16) unsigned char xs[LDS_BYTES];
  const int bid = blockIdx.x;
  const int ch = bid & 63;          // all 8 pieces of a channel share bid%8 -> same XCD
  const int T0 = (bid >> 6) << 15;
  const float* xch = x + (size_t)ch * T_LEN;
  const char* btc = (const char*)btf + (size_t)ch * NCHUNK * 1024;

  const int tid = threadIdx.x;
  const int lane = tid & 63;
  const int w = tid >> 6;

  // ---- A staging: block n (8 elems at x[T0-4000+8n]) -> LDS slot sigma(n)
  for (int n = tid; n < WBLK; n += 256) {
    int gi = T0 - 4000 + 8 * n;
    float v0, v1, v2, v3, v4, v5, v6, v7;
    if (gi >= 0 && gi + 8 <= T_LEN) {
      float4 a = *(const float4*)(xch + gi);
      float4 b = *(const float4*)(xch + gi + 4);
      v0 = a.x; v1 = a.y; v2 = a.z; v3 = a.w;
      v4 = b.x; v5 = b.y; v6 = b.z; v7 = b.w;
    } else {
      v0 = (gi + 0 >= 0 && gi + 0 < T_LEN) ? xch[gi + 0] : 0.f;
      v1 = (gi + 1 >= 0 && gi + 1 < T_LEN) ? xch[gi + 1] : 0.f;
      v2 = (gi + 2 >= 0 && gi + 2 < T_LEN) ? xch[gi + 2] : 0.f;
      v3 = (gi + 3 >= 0 && gi + 3 < T_LEN) ? xch[gi + 3] : 0.f;
      v4 = (gi + 4 >= 0 && gi + 4 < T_LEN) ? xch[gi + 4] : 0.f;
      v5 = (gi + 5 >= 0 && gi + 5 < T_LEN) ? xch[gi + 5] : 0.f;
      v6 = (gi + 6 >= 0 && gi + 6 < T_LEN) ? xch[gi + 6] : 0.f;
      v7 = (gi + 7 >= 0 && gi + 7 < T_LEN) ? xch[gi + 7] : 0.f;
    }
    uint4 pk;
    pk.x = (unsigned int)f2bf(v0) | ((unsigned int)f2bf(v1) << 16);
    pk.y = (unsigned int)f2bf(v2) | ((unsigned int)f2bf(v3) << 16);
    pk.z = (unsigned int)f2bf(v4) | ((unsigned int)f2bf(v5) << 16);
    pk.w = (unsigned int)f2bf(v6) | ((unsigned int)f2bf(v7) << 16);
    int sig = (n >> 5) + SIG_M * (n & 31);
    *(uint4*)(xs + 16 * sig) = pk;
  }
  __syncthreads();

  const int l31 = lane & 31;
  const int h = lane >> 5;
  // beta = 1024w + 32*l31 + 2q + h; sigma = (32w + l31 + 145h) + [(q>>4) + 290*(q&15)]
  const unsigned abase = 16u * (32 * w + l31 + SIG_M * h);

  auto aread = [&](int q) -> bf16x8 {
    unsigned off = 16u * ((unsigned)(q >> 4) + 290u * (unsigned)(q & 15));
    return *(const bf16x8*)(xs + abase + off);
  };
  auto bloadc = [&](int t) -> bf16x8 {
    int tc = t > 252 ? 252 : t;   // T[252] is all-zero padding
    return *(const bf16x8*)(btc + (size_t)tc * 1024 + lane * 16);
  };

  f32x16 acc[8] = {};
  bf16x8 zero8 = {};
  bf16x8 E0 = bloadc(0), E1 = zero8, E2 = zero8, E3 = zero8,
         E4 = zero8, E5 = zero8, E6 = zero8, E7 = zero8;
  bf16x8 O0 = bloadc(1), O1 = zero8, O2 = zero8, O3 = zero8,
         O4 = zero8, O5 = zero8, O6 = zero8, O7 = zero8;
  bf16x8 a_cur = aread(0);

#define DO_STEP(R0, R1, R2, R3, R4, R5, R6, R7, QQ)                                      \
  {                                                                                      \
    bf16x8 nb = bloadc((QQ) + 2);                                                        \
    bf16x8 an = aread((QQ) + 1);                                                         \
    __builtin_amdgcn_s_setprio(1);                                                       \
    acc[0] = __builtin_amdgcn_mfma_f32_32x32x16_bf16(a_cur, R0, acc[0], 0, 0, 0);        \
    acc[1] = __builtin_amdgcn_mfma_f32_32x32x16_bf16(a_cur, R1, acc[1], 0, 0, 0);        \
    acc[2] = __builtin_amdgcn_mfma_f32_32x32x16_bf16(a_cur, R2, acc[2], 0, 0, 0);        \
    acc[3] = __builtin_amdgcn_mfma_f32_32x32x16_bf16(a_cur, R3, acc[3], 0, 0, 0);        \
    acc[4] = __builtin_amdgcn_mfma_f32_32x32x16_bf16(a_cur, R4, acc[4], 0, 0, 0);        \
    acc[5] = __builtin_amdgcn_mfma_f32_32x32x16_bf16(a_cur, R5, acc[5], 0, 0, 0);        \
    acc[6] = __builtin_amdgcn_mfma_f32_32x32x16_bf16(a_cur, R6, acc[6], 0, 0, 0);        \
    acc[7] = __builtin_amdgcn_mfma_f32_32x32x16_bf16(a_cur, R7, acc[7], 0, 0, 0);        \
    __builtin_amdgcn_s_setprio(0);                                                       \
    R7 = R6; R6 = R5; R5 = R4; R4 = R3; R3 = R2; R2 = R1; R1 = R0; R0 = nb;              \
    a_cur = an;                                                                          \
  }

#pragma unroll 8
  for (int q = 0; q < NSTEP; q += 2) {
    DO_STEP(E0, E1, E2, E3, E4, E5, E6, E7, q);
    DO_STEP(O0, O1, O2, O3, O4, O5, O6, O7, q + 1);
  }
#undef DO_STEP

  // C/D layout: col j = lane&31, row i = (r&3) + 8*(r>>2) + 4*h
  float* och = out + (size_t)ch * T_LEN + T0 + 8192 * w;
#pragma unroll
  for (int c = 0; c < 8; ++c) {
#pragma unroll
    for (int r = 0; r < 16; ++r) {
      int irow = (r & 3) + 8 * (r >> 2) + 4 * h;
      och[256 * irow + 32 * c + l31] = acc[c][r];
    }
  }
}

extern "C" void kernel_launch(void* const* d_in, const int* in_sizes, int n_in,
                              void* d_out, int out_size, void* d_ws, size_t ws_size,
                              hipStream_t stream) {
  const float* onsets  = (const float*)d_in[0];
  const float* sources = (const float*)d_in[1];
  unsigned short* btf  = (unsigned short*)d_ws;   // 64*253*64*8*2 = 16,580,608 B
  float* out = (float*)d_out;

  int nthr = NCH * NCHUNK * 64;
  build_btf<<<(nthr + 255) / 256, 256, 0, stream>>>(sources, btf);
  conv_main<<<512, 256, 0, stream>>>(onsets, btf, out);
}